// Round 4
// baseline (569.595 us; speedup 1.0000x reference)
//
#include <hip/hip_runtime.h>
#include <stdint.h>

#define NN 100000   // nodes
#define NK 10       // sampled neighbors
#define D  256      // hidden dim
#define D2 512      // concat dim
#define MT 16       // nodes per block; 100000/16 = 6250 exactly -> no tails

typedef short bf16x8 __attribute__((ext_vector_type(8)));   // 8 bf16 (4 VGPRs)
typedef float f32x4  __attribute__((ext_vector_type(4)));

__device__ __forceinline__ uint16_t f2bf(float f) {
  uint32_t u = __float_as_uint(f);
  u += 0x7fffu + ((u >> 16) & 1u);   // round-to-nearest-even
  return (uint16_t)(u >> 16);
}
__device__ __forceinline__ uint32_t pack2(float a, float b) {
  return (uint32_t)f2bf(a) | ((uint32_t)f2bf(b) << 16);
}

// ---------------------------------------------------------------------------
// Pack W [512][256] f32 into bf16 B-fragment lane order for
// mfma_f32_16x16x32_bf16: Wp[kstep][ntile][lane][j] = bf16(W[kstep*32+(lane>>4)*8+j]
//                                                         [ntile*16+(lane&15)])
// ---------------------------------------------------------------------------
__global__ void pack_w(const float* __restrict__ W, uint16_t* __restrict__ Wp) {
  int idx   = blockIdx.x * blockDim.x + threadIdx.x;  // 0..16383
  int lane  = idx & 63;
  int ntile = (idx >> 6) & 15;
  int kstep = idx >> 10;
  int n  = ntile * 16 + (lane & 15);
  int k0 = kstep * 32 + (lane >> 4) * 8;
  float v[8];
#pragma unroll
  for (int j = 0; j < 8; j++) v[j] = W[(size_t)(k0 + j) * D + n];
  uint4 o;
  o.x = pack2(v[0], v[1]);
  o.y = pack2(v[2], v[3]);
  o.z = pack2(v[4], v[5]);
  o.w = pack2(v[6], v[7]);
  ((uint4*)Wp)[idx] = o;
}

// ---------------------------------------------------------------------------
// Fused SAGE layer: gather+mean -> LDS concat tile (bf16) -> MFMA -> bias/ReLU.
// LDS tile: 16 rows x 512 k bf16 = 16 KB -> 8 blocks/CU = 32 waves/CU (100%).
// XOR swizzle on 16B chunks: chunk' = chunk ^ (row & 15).
// ---------------------------------------------------------------------------
template <bool IN_BF16, bool OUT_BF16>
__global__ __launch_bounds__(256, 8) void sage_layer(
    const void* __restrict__ hin_v,
    const int*  __restrict__ adj,     // [NN][NK]
    const uint16_t* __restrict__ Wp,  // packed bf16 W [16][16][64][8]
    const float* __restrict__ bias,   // [D] f32
    void*       __restrict__ hout_v,
    const int relu)
{
  __shared__ uint4 lds4[MT * 64];     // 16 rows * 64 chunks * 16B = 16 KB
  const int t  = threadIdx.x;
  const int m0 = blockIdx.x * MT;

  // ---- phase 1: self rows -> chunks 0..31 (k = 0..255) ----
#pragma unroll
  for (int i = 0; i < 2; i++) {
    int cidx = t + i * 256;           // 0..511
    int r = cidx >> 5;                // row 0..15
    int c = cidx & 31;                // chunk 0..31 (8 elems each)
    uint4 o;
    int node = m0 + r;
    if (IN_BF16) {
      o = *(const uint4*)((const uint16_t*)hin_v + (size_t)node * D + c * 8);
    } else {
      const float4* p = (const float4*)((const float*)hin_v + (size_t)node * D + c * 8);
      float4 v0 = p[0], v1 = p[1];
      o.x = pack2(v0.x, v0.y); o.y = pack2(v0.z, v0.w);
      o.z = pack2(v1.x, v1.y); o.w = pack2(v1.z, v1.w);
    }
    lds4[r * 64 + (c ^ (r & 15))] = o;
  }

  // ---- phase 2: neighbor mean -> chunks 32..63 (k = 256..511) ----
  {
    const int half = t >> 5;          // 0..7
    const int l32  = t & 31;          // 32 lanes cover 256 elems (8 each)
#pragma unroll 1
    for (int i = 0; i < 2; i++) {
      int r = i * 8 + half;
      int node = m0 + r;
      float a0=0.f,a1=0.f,a2=0.f,a3=0.f,a4=0.f,a5=0.f,a6=0.f,a7=0.f;
#pragma unroll
      for (int k = 0; k < NK; k++) {
        int nb = adj[node * NK + k];
        if (IN_BF16) {
          uint4 v = *(const uint4*)((const uint16_t*)hin_v + (size_t)nb * D + l32 * 8);
          a0 += __uint_as_float(v.x << 16);
          a1 += __uint_as_float(v.x & 0xffff0000u);
          a2 += __uint_as_float(v.y << 16);
          a3 += __uint_as_float(v.y & 0xffff0000u);
          a4 += __uint_as_float(v.z << 16);
          a5 += __uint_as_float(v.z & 0xffff0000u);
          a6 += __uint_as_float(v.w << 16);
          a7 += __uint_as_float(v.w & 0xffff0000u);
        } else {
          const float4* p = (const float4*)((const float*)hin_v + (size_t)nb * D + l32 * 8);
          float4 v0 = p[0], v1 = p[1];
          a0 += v0.x; a1 += v0.y; a2 += v0.z; a3 += v0.w;
          a4 += v1.x; a5 += v1.y; a6 += v1.z; a7 += v1.w;
        }
      }
      const float s = 1.0f / (float)NK;
      uint4 o;
      o.x = pack2(a0 * s, a1 * s);
      o.y = pack2(a2 * s, a3 * s);
      o.z = pack2(a4 * s, a5 * s);
      o.w = pack2(a6 * s, a7 * s);
      int c = 32 + l32;
      lds4[r * 64 + (c ^ (r & 15))] = o;
    }
  }

  __syncthreads();

  // ---- phase 3: GEMM  [16 x 512] @ [512 x 256] ----
  const int w    = t >> 6;   // wave 0..3 -> output cols w*64 .. w*64+63
  const int l    = t & 63;
  const int quad = l >> 4;
  const int l16  = l & 15;

  f32x4 acc[4];
#pragma unroll
  for (int nt = 0; nt < 4; nt++)
    acc[nt] = (f32x4){0.f, 0.f, 0.f, 0.f};

  const uint4* wp4 = (const uint4*)Wp;

#pragma unroll 2
  for (int ks = 0; ks < 16; ks++) {
    bf16x8 af, bfr[4];
    {
      int row = l16;                           // A: m = lane&15
      int c   = ks * 4 + quad;                 // A: k = quad*8 + j
      af = *((const bf16x8*)&lds4[row * 64 + (c ^ (row & 15))]);
    }
#pragma unroll
    for (int nt = 0; nt < 4; nt++) {
      bfr[nt] = *((const bf16x8*)&wp4[(ks * 16 + (w * 4 + nt)) * 64 + l]);
    }
#pragma unroll
    for (int nt = 0; nt < 4; nt++)
      acc[nt] = __builtin_amdgcn_mfma_f32_16x16x32_bf16(af, bfr[nt], acc[nt], 0, 0, 0);
  }

  // ---- epilogue: bias (+ReLU) -> store ----
#pragma unroll
  for (int i = 0; i < 4; i++) {
    int rr = m0 + quad * 4 + i;                // C/D: row = quad*4 + reg
#pragma unroll
    for (int nt = 0; nt < 4; nt++) {
      int col = w * 64 + nt * 16 + l16;        // C/D: col = lane&15
      float v = acc[nt][i] + bias[col];
      if (relu) v = fmaxf(v, 0.0f);
      if (OUT_BF16)
        ((uint16_t*)hout_v)[(size_t)rr * D + col] = f2bf(v);
      else
        ((float*)hout_v)[(size_t)rr * D + col] = v;
    }
  }
}

extern "C" void kernel_launch(void* const* d_in, const int* in_sizes, int n_in,
                              void* d_out, int out_size, void* d_ws, size_t ws_size,
                              hipStream_t stream) {
  const float* x   = (const float*)d_in[0];
  const int*   adj = (const int*)d_in[1];
  const float* W0  = (const float*)d_in[2];
  const float* b0  = (const float*)d_in[3];
  const float* W1  = (const float*)d_in[4];
  const float* b1  = (const float*)d_in[5];
  const float* W2  = (const float*)d_in[6];
  const float* b2  = (const float*)d_in[7];
  float* out = (float*)d_out;

  uint16_t* ws  = (uint16_t*)d_ws;
  uint16_t* Wp0 = ws;                    // 512*256 bf16 = 256 KB each
  uint16_t* Wp1 = Wp0 + D2 * D;
  uint16_t* Wp2 = Wp1 + D2 * D;
  uint16_t* hB  = Wp2 + D2 * D;          // [NN][D] bf16 = 51.2 MB (in ws)
  // hA aliases d_out's first 51.2 MB (d_out is 102.4 MB f32; layer 2 reads hB
  // from ws while overwriting d_out, so no read-write overlap).
  uint16_t* hA  = (uint16_t*)d_out;

  pack_w<<<64, 256, 0, stream>>>(W0, Wp0);
  pack_w<<<64, 256, 0, stream>>>(W1, Wp1);
  pack_w<<<64, 256, 0, stream>>>(W2, Wp2);

  const int grid = NN / MT;              // 6250 blocks, exact
  sage_layer<false, true ><<<grid, 256, 0, stream>>>(x,  adj, Wp0, b0, hA,  1);
  sage_layer<true,  true ><<<grid, 256, 0, stream>>>(hA, adj, Wp1, b1, hB,  1);
  sage_layer<true,  false><<<grid, 256, 0, stream>>>(hB, adj, Wp2, b2, out, 0);
}

// Round 5
// 477.245 us; speedup vs baseline: 1.1935x; 1.1935x over previous
//
#include <hip/hip_runtime.h>
#include <stdint.h>

#define NN 100000   // nodes
#define NK 10       // sampled neighbors
#define D  256      // hidden dim
#define D2 512      // concat dim
#define MT 32       // nodes per block; 100000/32 = 3125 exactly -> no tails

typedef short bf16x8 __attribute__((ext_vector_type(8)));   // 8 bf16 (4 VGPRs)
typedef float f32x4  __attribute__((ext_vector_type(4)));

__device__ __forceinline__ uint16_t f2bf(float f) {
  uint32_t u = __float_as_uint(f);
  u += 0x7fffu + ((u >> 16) & 1u);   // round-to-nearest-even
  return (uint16_t)(u >> 16);
}
__device__ __forceinline__ uint32_t pack2(float a, float b) {
  return (uint32_t)f2bf(a) | ((uint32_t)f2bf(b) << 16);
}

// ---------------------------------------------------------------------------
// Streaming f32 -> bf16 convert: x [NN*D] -> xb. float2 in / uint out per
// thread, fully coalesced. 12.8M threads = 50000 blocks x 256.
// ---------------------------------------------------------------------------
__global__ void convert_x(const float2* __restrict__ in, uint32_t* __restrict__ out) {
  int idx = blockIdx.x * blockDim.x + threadIdx.x;   // 0 .. NN*D/2-1
  float2 v = in[idx];
  out[idx] = pack2(v.x, v.y);
}

// ---------------------------------------------------------------------------
// Pack W [512][256] f32 into bf16 B-fragment lane order for
// mfma_f32_16x16x32_bf16: Wp[kstep][ntile][lane][j] = bf16(W[kstep*32+(lane>>4)*8+j]
//                                                         [ntile*16+(lane&15)])
// ---------------------------------------------------------------------------
__global__ void pack_w(const float* __restrict__ W, uint16_t* __restrict__ Wp) {
  int idx   = blockIdx.x * blockDim.x + threadIdx.x;  // 0..16383
  int lane  = idx & 63;
  int ntile = (idx >> 6) & 15;
  int kstep = idx >> 10;
  int n  = ntile * 16 + (lane & 15);
  int k0 = kstep * 32 + (lane >> 4) * 8;
  float v[8];
#pragma unroll
  for (int j = 0; j < 8; j++) v[j] = W[(size_t)(k0 + j) * D + n];
  uint4 o;
  o.x = pack2(v[0], v[1]);
  o.y = pack2(v[2], v[3]);
  o.z = pack2(v[4], v[5]);
  o.w = pack2(v[6], v[7]);
  ((uint4*)Wp)[idx] = o;
}

// ---------------------------------------------------------------------------
// Fused SAGE layer (all-bf16 input table): gather+mean -> LDS concat tile ->
// MFMA -> bias/ReLU. LDS: 32 rows x 512 k bf16 = 32 KB -> 5 blocks/CU.
// XOR swizzle on 16B chunks: chunk' = chunk ^ (row & 15).
// ---------------------------------------------------------------------------
template <bool OUT_BF16>
__global__ __launch_bounds__(256, 5) void sage_layer(
    const uint16_t* __restrict__ hin,   // [NN][D] bf16
    const int*      __restrict__ adj,   // [NN][NK]
    const uint16_t* __restrict__ Wp,    // packed bf16 W [16][16][64][8]
    const float*    __restrict__ bias,  // [D] f32
    void*           __restrict__ hout_v,
    const int relu)
{
  __shared__ uint4 lds4[MT * 64];     // 32 rows * 64 chunks * 16B = 32 KB
  const int t  = threadIdx.x;
  const int m0 = blockIdx.x * MT;

  // ---- phase 1: self rows -> chunks 0..31 (k = 0..255) ----
#pragma unroll
  for (int i = 0; i < 4; i++) {
    int cidx = t + i * 256;           // 0..1023
    int r = cidx >> 5;                // row 0..31
    int c = cidx & 31;                // chunk 0..31 (8 elems each)
    int node = m0 + r;
    uint4 o = *(const uint4*)(hin + (size_t)node * D + c * 8);
    lds4[r * 64 + (c ^ (r & 15))] = o;
  }

  // ---- phase 2: neighbor mean -> chunks 32..63 (k = 256..511) ----
  {
    const int half = t >> 5;          // 0..7
    const int l32  = t & 31;          // 32 lanes cover 256 elems (8 each)
#pragma unroll 1
    for (int i = 0; i < 4; i++) {
      int r = i * 8 + half;
      int node = m0 + r;
      float a0=0.f,a1=0.f,a2=0.f,a3=0.f,a4=0.f,a5=0.f,a6=0.f,a7=0.f;
#pragma unroll
      for (int k = 0; k < NK; k++) {
        int nb = adj[node * NK + k];
        uint4 v = *(const uint4*)(hin + (size_t)nb * D + l32 * 8);
        a0 += __uint_as_float(v.x << 16);
        a1 += __uint_as_float(v.x & 0xffff0000u);
        a2 += __uint_as_float(v.y << 16);
        a3 += __uint_as_float(v.y & 0xffff0000u);
        a4 += __uint_as_float(v.z << 16);
        a5 += __uint_as_float(v.z & 0xffff0000u);
        a6 += __uint_as_float(v.w << 16);
        a7 += __uint_as_float(v.w & 0xffff0000u);
      }
      const float s = 1.0f / (float)NK;
      uint4 o;
      o.x = pack2(a0 * s, a1 * s);
      o.y = pack2(a2 * s, a3 * s);
      o.z = pack2(a4 * s, a5 * s);
      o.w = pack2(a6 * s, a7 * s);
      int c = 32 + l32;
      lds4[r * 64 + (c ^ (r & 15))] = o;
    }
  }

  __syncthreads();

  // ---- phase 3: GEMM  [32 x 512] @ [512 x 256] ----
  const int w    = t >> 6;   // wave 0..3 -> output cols w*64 .. w*64+63
  const int l    = t & 63;
  const int quad = l >> 4;
  const int l16  = l & 15;

  f32x4 acc[2][4];
#pragma unroll
  for (int mt = 0; mt < 2; mt++)
#pragma unroll
    for (int nt = 0; nt < 4; nt++)
      acc[mt][nt] = (f32x4){0.f, 0.f, 0.f, 0.f};

  const uint4* wp4 = (const uint4*)Wp;

#pragma unroll 2
  for (int ks = 0; ks < 16; ks++) {
    bf16x8 af[2], bfr[4];
#pragma unroll
    for (int mt = 0; mt < 2; mt++) {
      int row = mt * 16 + l16;                 // A: m = lane&15
      int c   = ks * 4 + quad;                 // A: k = quad*8 + j
      af[mt] = *((const bf16x8*)&lds4[row * 64 + (c ^ (row & 15))]);
    }
#pragma unroll
    for (int nt = 0; nt < 4; nt++) {
      bfr[nt] = *((const bf16x8*)&wp4[(ks * 16 + (w * 4 + nt)) * 64 + l]);
    }
#pragma unroll
    for (int mt = 0; mt < 2; mt++)
#pragma unroll
      for (int nt = 0; nt < 4; nt++)
        acc[mt][nt] = __builtin_amdgcn_mfma_f32_16x16x32_bf16(
            af[mt], bfr[nt], acc[mt][nt], 0, 0, 0);
  }

  // ---- epilogue: bias (+ReLU) -> store ----
#pragma unroll
  for (int mt = 0; mt < 2; mt++) {
#pragma unroll
    for (int i = 0; i < 4; i++) {
      int rr = m0 + mt * 16 + quad * 4 + i;    // C/D: row = quad*4 + reg
#pragma unroll
      for (int nt = 0; nt < 4; nt++) {
        int col = w * 64 + nt * 16 + l16;      // C/D: col = lane&15
        float v = acc[mt][nt][i] + bias[col];
        if (relu) v = fmaxf(v, 0.0f);
        if (OUT_BF16)
          ((uint16_t*)hout_v)[(size_t)rr * D + col] = f2bf(v);
        else
          ((float*)hout_v)[(size_t)rr * D + col] = v;
      }
    }
  }
}

extern "C" void kernel_launch(void* const* d_in, const int* in_sizes, int n_in,
                              void* d_out, int out_size, void* d_ws, size_t ws_size,
                              hipStream_t stream) {
  const float* x   = (const float*)d_in[0];
  const int*   adj = (const int*)d_in[1];
  const float* W0  = (const float*)d_in[2];
  const float* b0  = (const float*)d_in[3];
  const float* W1  = (const float*)d_in[4];
  const float* b1  = (const float*)d_in[5];
  const float* W2  = (const float*)d_in[6];
  const float* b2  = (const float*)d_in[7];
  float* out = (float*)d_out;

  // ws layout (103.2 MB total, same footprint as the round-1 run):
  //   Wp0/Wp1/Wp2: 256 KB each
  //   hA:          [NN][D] bf16 = 51.2 MB
  //   xb/hB:       [NN][D] bf16 = 51.2 MB  (xb dead after layer 0; hB reuses it)
  uint16_t* ws  = (uint16_t*)d_ws;
  uint16_t* Wp0 = ws;
  uint16_t* Wp1 = Wp0 + D2 * D;
  uint16_t* Wp2 = Wp1 + D2 * D;
  uint16_t* hA  = Wp2 + D2 * D;
  uint16_t* xb  = hA + (size_t)NN * D;
  uint16_t* hB  = xb;   // aliases xb (safe: xb fully consumed by layer 0)

  convert_x<<<NN * D / 512, 256, 0, stream>>>((const float2*)x, (uint32_t*)xb);
  pack_w<<<64, 256, 0, stream>>>(W0, Wp0);
  pack_w<<<64, 256, 0, stream>>>(W1, Wp1);
  pack_w<<<64, 256, 0, stream>>>(W2, Wp2);

  const int grid = NN / MT;              // 3125 blocks, exact
  sage_layer<true ><<<grid, 256, 0, stream>>>(xb, adj, Wp0, b0, hA,  1);
  sage_layer<true ><<<grid, 256, 0, stream>>>(hA, adj, Wp1, b1, hB,  1);
  sage_layer<false><<<grid, 256, 0, stream>>>(hB, adj, Wp2, b2, out, 0);
}

// Round 6
// 457.091 us; speedup vs baseline: 1.2461x; 1.0441x over previous
//
#include <hip/hip_runtime.h>
#include <stdint.h>

#define NN 100000   // nodes
#define NK 10       // sampled neighbors
#define D  256      // hidden dim
#define D2 512      // concat dim
#define MT 32       // nodes per block; 100000/32 = 3125 exactly -> no tails

typedef short bf16x8 __attribute__((ext_vector_type(8)));   // 8 bf16 (4 VGPRs)
typedef float f32x4  __attribute__((ext_vector_type(4)));

__device__ __forceinline__ uint16_t f2bf(float f) {
  uint32_t u = __float_as_uint(f);
  u += 0x7fffu + ((u >> 16) & 1u);   // round-to-nearest-even
  return (uint16_t)(u >> 16);
}
__device__ __forceinline__ uint32_t pack2(float a, float b) {
  return (uint32_t)f2bf(a) | ((uint32_t)f2bf(b) << 16);
}

// ---------------------------------------------------------------------------
// Quantize x rows to int8 + per-row scale. One 64-lane wave per row.
// ---------------------------------------------------------------------------
__global__ __launch_bounds__(256) void quant_x(const float* __restrict__ x,
                                               uint8_t* __restrict__ q8,
                                               float*   __restrict__ qs) {
  int node = blockIdx.x * 4 + (threadIdx.x >> 6);
  int lane = threadIdx.x & 63;
  const float4 v = *(const float4*)(x + (size_t)node * D + lane * 4);
  float m = fmaxf(fmaxf(fabsf(v.x), fabsf(v.y)), fmaxf(fabsf(v.z), fabsf(v.w)));
#pragma unroll
  for (int d = 1; d < 64; d <<= 1) m = fmaxf(m, __shfl_xor(m, d, 64));
  float inv = m > 1e-30f ? 127.0f / m : 0.0f;
  int q0 = (int)rintf(v.x * inv), q1 = (int)rintf(v.y * inv);
  int q2 = (int)rintf(v.z * inv), q3 = (int)rintf(v.w * inv);
  uint32_t p = (uint32_t)(q0 & 0xff) | ((uint32_t)(q1 & 0xff) << 8) |
               ((uint32_t)(q2 & 0xff) << 16) | ((uint32_t)(q3 & 0xff) << 24);
  ((uint32_t*)(q8 + (size_t)node * D))[lane] = p;
  if (lane == 0) qs[node] = m * (1.0f / 127.0f);
}

// ---------------------------------------------------------------------------
// Pack W [512][256] f32 into bf16 B-fragment lane order for
// mfma_f32_16x16x32_bf16.
// ---------------------------------------------------------------------------
__global__ void pack_w(const float* __restrict__ W, uint16_t* __restrict__ Wp) {
  int idx   = blockIdx.x * blockDim.x + threadIdx.x;  // 0..16383
  int lane  = idx & 63;
  int ntile = (idx >> 6) & 15;
  int kstep = idx >> 10;
  int n  = ntile * 16 + (lane & 15);
  int k0 = kstep * 32 + (lane >> 4) * 8;
  float v[8];
#pragma unroll
  for (int j = 0; j < 8; j++) v[j] = W[(size_t)(k0 + j) * D + n];
  uint4 o;
  o.x = pack2(v[0], v[1]);
  o.y = pack2(v[2], v[3]);
  o.z = pack2(v[4], v[5]);
  o.w = pack2(v[6], v[7]);
  ((uint4*)Wp)[idx] = o;
}

// ---------------------------------------------------------------------------
// Fused SAGE layer: self rows (bf16 or f32 table) + int8 gather-mean ->
// LDS concat tile (bf16) -> MFMA -> bias(+ReLU) -> store.
// QOUT layers (0,1): ReLU + write bf16 table + int8 table + row scales.
// !QOUT (layer 2):   no ReLU, write f32 to d_out.
// LDS: 32 rows x 512 k bf16 = 32 KB -> 5 blocks/CU. XOR swizzle on 16B chunks.
// ---------------------------------------------------------------------------
template <bool SELF_F32, bool QOUT>
__global__ __launch_bounds__(256, 5) void sage_layer(
    const void*     __restrict__ hin_v,  // self table: f32 or bf16 [NN][D]
    const uint8_t*  __restrict__ qtab,   // gather table int8 [NN][D]
    const float*    __restrict__ qsc,    // [NN] gather row scales
    const int*      __restrict__ adj,    // [NN][NK]
    const uint16_t* __restrict__ Wp,     // packed bf16 W [16][16][64][8]
    const float*    __restrict__ bias,   // [D] f32
    void*           __restrict__ hout_v, // bf16 (QOUT) / f32 (!QOUT)
    uint8_t*        __restrict__ q8out,  // int8 table out (QOUT)
    float*          __restrict__ qsout)  // row scales out (QOUT)
{
  __shared__ uint4 lds4[MT * 64];        // 32 rows * 64 chunks * 16B = 32 KB
  const int t  = threadIdx.x;
  const int m0 = blockIdx.x * MT;

  // ---- phase 1: self rows -> chunks 0..31 (k = 0..255) ----
#pragma unroll
  for (int i = 0; i < 4; i++) {
    int cidx = t + i * 256;           // 0..1023
    int r = cidx >> 5;                // row 0..31
    int c = cidx & 31;                // chunk 0..31 (8 elems each)
    int node = m0 + r;
    uint4 o;
    if (SELF_F32) {
      const float4* p = (const float4*)((const float*)hin_v + (size_t)node * D + c * 8);
      float4 v0 = p[0], v1 = p[1];
      o.x = pack2(v0.x, v0.y); o.y = pack2(v0.z, v0.w);
      o.z = pack2(v1.x, v1.y); o.w = pack2(v1.z, v1.w);
    } else {
      o = *(const uint4*)((const uint16_t*)hin_v + (size_t)node * D + c * 8);
    }
    lds4[r * 64 + (c ^ (r & 15))] = o;
  }

  // ---- phase 2: int8 gather + mean -> chunks 32..63 (k = 256..511) ----
  {
    const int half = t >> 5;          // 0..7
    const int l32  = t & 31;          // 32 lanes cover 256 elems (8 each)
#pragma unroll 1
    for (int i = 0; i < 4; i++) {
      int r = i * 8 + half;
      int node = m0 + r;
      float a0=0.f,a1=0.f,a2=0.f,a3=0.f,a4=0.f,a5=0.f,a6=0.f,a7=0.f;
#pragma unroll
      for (int k = 0; k < NK; k++) {
        int nb = adj[node * NK + k];
        float s = qsc[nb];
        uint2 v = *(const uint2*)(qtab + (size_t)nb * D + l32 * 8);
        a0 += s * (float)(int8_t)(v.x);
        a1 += s * (float)(int8_t)(v.x >> 8);
        a2 += s * (float)(int8_t)(v.x >> 16);
        a3 += s * (float)(int8_t)(v.x >> 24);
        a4 += s * (float)(int8_t)(v.y);
        a5 += s * (float)(int8_t)(v.y >> 8);
        a6 += s * (float)(int8_t)(v.y >> 16);
        a7 += s * (float)(int8_t)(v.y >> 24);
      }
      const float sc = 1.0f / (float)NK;
      uint4 o;
      o.x = pack2(a0 * sc, a1 * sc);
      o.y = pack2(a2 * sc, a3 * sc);
      o.z = pack2(a4 * sc, a5 * sc);
      o.w = pack2(a6 * sc, a7 * sc);
      int c = 32 + l32;
      lds4[r * 64 + (c ^ (r & 15))] = o;
    }
  }

  __syncthreads();

  // ---- phase 3: GEMM  [32 x 512] @ [512 x 256] ----
  const int w    = t >> 6;   // wave 0..3 -> output cols w*64 .. w*64+63
  const int l    = t & 63;
  const int quad = l >> 4;
  const int l16  = l & 15;

  f32x4 acc[2][4];
#pragma unroll
  for (int mt = 0; mt < 2; mt++)
#pragma unroll
    for (int nt = 0; nt < 4; nt++)
      acc[mt][nt] = (f32x4){0.f, 0.f, 0.f, 0.f};

  const uint4* wp4 = (const uint4*)Wp;

#pragma unroll 2
  for (int ks = 0; ks < 16; ks++) {
    bf16x8 af[2], bfr[4];
#pragma unroll
    for (int mt = 0; mt < 2; mt++) {
      int row = mt * 16 + l16;                 // A: m = lane&15
      int c   = ks * 4 + quad;                 // A: k = quad*8 + j
      af[mt] = *((const bf16x8*)&lds4[row * 64 + (c ^ (row & 15))]);
    }
#pragma unroll
    for (int nt = 0; nt < 4; nt++) {
      bfr[nt] = *((const bf16x8*)&wp4[(ks * 16 + (w * 4 + nt)) * 64 + l]);
    }
#pragma unroll
    for (int mt = 0; mt < 2; mt++)
#pragma unroll
      for (int nt = 0; nt < 4; nt++)
        acc[mt][nt] = __builtin_amdgcn_mfma_f32_16x16x32_bf16(
            af[mt], bfr[nt], acc[mt][nt], 0, 0, 0);
  }

  // ---- epilogue: bias (+ReLU), row-scale quant (QOUT), store ----
  float lmax[2][4];
#pragma unroll
  for (int mt = 0; mt < 2; mt++)
#pragma unroll
    for (int i = 0; i < 4; i++) lmax[mt][i] = 0.0f;

#pragma unroll
  for (int mt = 0; mt < 2; mt++)
#pragma unroll
    for (int nt = 0; nt < 4; nt++)
#pragma unroll
      for (int i = 0; i < 4; i++) {
        int col = w * 64 + nt * 16 + l16;      // C/D: col = lane&15
        float v = acc[mt][nt][i] + bias[col];
        if (QOUT) v = fmaxf(v, 0.0f);          // ReLU on layers 0,1
        acc[mt][nt][i] = v;
        if (QOUT) lmax[mt][i] = fmaxf(lmax[mt][i], v);
      }

  float inv[2][4];
  if (QOUT) {
    // reduce rowmax across the 16 lanes of each quad-group
#pragma unroll
    for (int d = 1; d < 16; d <<= 1)
#pragma unroll
      for (int mt = 0; mt < 2; mt++)
#pragma unroll
        for (int i = 0; i < 4; i++)
          lmax[mt][i] = fmaxf(lmax[mt][i], __shfl_xor(lmax[mt][i], d, 64));
    __syncthreads();                            // lds4 dead -> reuse for rowmax
    float* rmax = (float*)lds4;                 // [32 rows][4 waves]
    if (l16 == 0) {
#pragma unroll
      for (int mt = 0; mt < 2; mt++)
#pragma unroll
        for (int i = 0; i < 4; i++)
          rmax[(mt * 16 + quad * 4 + i) * 4 + w] = lmax[mt][i];
    }
    __syncthreads();
#pragma unroll
    for (int mt = 0; mt < 2; mt++)
#pragma unroll
      for (int i = 0; i < 4; i++) {
        int row = mt * 16 + quad * 4 + i;
        float m = fmaxf(fmaxf(rmax[row * 4 + 0], rmax[row * 4 + 1]),
                        fmaxf(rmax[row * 4 + 2], rmax[row * 4 + 3]));
        inv[mt][i] = m > 1e-30f ? 127.0f / m : 0.0f;
        if (w == 0 && l16 == 0) qsout[m0 + row] = m * (1.0f / 127.0f);
      }
  }

#pragma unroll
  for (int mt = 0; mt < 2; mt++)
#pragma unroll
    for (int i = 0; i < 4; i++) {
      int rr = m0 + mt * 16 + quad * 4 + i;     // C/D: row = quad*4 + reg
#pragma unroll
      for (int nt = 0; nt < 4; nt++) {
        int col = w * 64 + nt * 16 + l16;
        float v = acc[mt][nt][i];
        if (QOUT) {
          ((uint16_t*)hout_v)[(size_t)rr * D + col] = f2bf(v);
          int q = (int)rintf(v * inv[mt][i]);
          q8out[(size_t)rr * D + col] = (uint8_t)(q & 0xff);
        } else {
          ((float*)hout_v)[(size_t)rr * D + col] = v;
        }
      }
    }
}

extern "C" void kernel_launch(void* const* d_in, const int* in_sizes, int n_in,
                              void* d_out, int out_size, void* d_ws, size_t ws_size,
                              hipStream_t stream) {
  const float* x   = (const float*)d_in[0];
  const int*   adj = (const int*)d_in[1];
  const float* W0  = (const float*)d_in[2];
  const float* b0  = (const float*)d_in[3];
  const float* W1  = (const float*)d_in[4];
  const float* b1  = (const float*)d_in[5];
  const float* W2  = (const float*)d_in[6];
  const float* b2  = (const float*)d_in[7];
  float* out = (float*)d_out;

  // d_out doubles as scratch until layer 2 overwrites it (102.4 MB exactly):
  //   hA  bf16 [NN][D] : bytes [0, 51.2e6)          written L0, read L1
  //   hA8 int8 [NN][D] : bytes [51.2e6, 76.8e6)     written L0, read L1
  //   x8  int8 [NN][D] : bytes [76.8e6, 102.4e6)    written quant_x, read L0
  uint8_t*  dob = (uint8_t*)d_out;
  uint16_t* hA  = (uint16_t*)dob;
  uint8_t*  hA8 = dob + 51200000;
  uint8_t*  x8  = dob + 76800000;

  // ws (~78.8 MB): Wp x3 + hB + hB8 + scales
  uint16_t* ws  = (uint16_t*)d_ws;
  uint16_t* Wp0 = ws;
  uint16_t* Wp1 = Wp0 + D2 * D;
  uint16_t* Wp2 = Wp1 + D2 * D;
  uint16_t* hB  = Wp2 + D2 * D;                      // bf16 [NN][D]
  uint8_t*  hB8 = (uint8_t*)(hB + (size_t)NN * D);   // int8 [NN][D]
  float*    xs  = (float*)(hB8 + (size_t)NN * D);    // [NN]
  float*    hAs = xs + NN;
  float*    hBs = hAs + NN;

  quant_x<<<NN / 4, 256, 0, stream>>>(x, x8, xs);
  pack_w<<<64, 256, 0, stream>>>(W0, Wp0);
  pack_w<<<64, 256, 0, stream>>>(W1, Wp1);
  pack_w<<<64, 256, 0, stream>>>(W2, Wp2);

  const int grid = NN / MT;              // 3125 blocks, exact
  sage_layer<true,  true ><<<grid, 256, 0, stream>>>(x,  x8,  xs,  adj, Wp0, b0, hA,  hA8, hAs);
  sage_layer<false, true ><<<grid, 256, 0, stream>>>(hA, hA8, hAs, adj, Wp1, b1, hB,  hB8, hBs);
  sage_layer<false, false><<<grid, 256, 0, stream>>>(hB, hB8, hBs, adj, Wp2, b2, out, nullptr, nullptr);
}